// Round 2
// baseline (2612.152 us; speedup 1.0000x reference)
//
#include <hip/hip_runtime.h>
#include <hip/hip_bf16.h>
#include <math.h>

#define NTOK 841          // 29*29 patches
#define BATCH 8
#define DIM 256
#define HEADS 8
#define DH 32
#define IMG 457
#define HPAD 464
#define ROWS (BATCH * NTOK)   // 6728

// ---------------------------------------------------------------------------
// SPT GEMM with fused tokenize gather:
// C[M=ROWS, N=256] = tok[M, K=1280] @ W[N,K]^T + bias + pos_emb
// tok[gm, k]: gm=(b,n), k=(c,py,px): value = xpad[b, (hp*16+py-dy_c)%464,
// (wp*16+px-dx_c)%464], xpad zero-padded 457->464.
// shifts (dx,dy): c0 (0,0), c1 (-8,-8), c2 (8,-8), c3 (-8,8), c4 (8,8)
// ---------------------------------------------------------------------------
__global__ __launch_bounds__(256) void spt_gemm_kernel(
    const float* __restrict__ x, const float* __restrict__ W,
    const float* __restrict__ bias, const float* __restrict__ posemb,
    float* __restrict__ C) {
    __shared__ float As[16][68];
    __shared__ float Ws[16][68];
    const int tid = threadIdx.x;
    const int nb = blockIdx.x, mb = blockIdx.y;
    const int lr = tid >> 2;            // 0..63
    const int lc = (tid & 3) * 4;       // 0,4,8,12
    const int tm0 = (tid >> 4) * 4;
    const int tn0 = (tid & 15) * 4;
    const int M = ROWS, N = DIM, K = 1280;

    // row decode for the A-load
    const int gm = mb * 64 + lr;
    const bool valid = gm < M;
    int b = 0, hp = 0, wp = 0;
    if (valid) {
        b = gm / NTOK;
        int n = gm - b * NTOK;
        hp = n / 29;
        wp = n - hp * 29;
    }
    const int dxs[5] = {0, -8, 8, -8, 8};
    const int dys[5] = {0, -8, -8, 8, 8};

    float acc[4][4];
#pragma unroll
    for (int i = 0; i < 4; i++)
#pragma unroll
        for (int j = 0; j < 4; j++) acc[i][j] = 0.0f;

    for (int kt = 0; kt < K / 16; kt++) {
        // gather A tile
        {
            int k0 = kt * 16 + lc;          // 4 consecutive k: same c, same py
            int c = k0 >> 8;
            int py = (k0 >> 4) & 15;
            int px0 = k0 & 15;              // px0..px0+3
            int r = hp * 16 + py - dys[c];
            r += (r < 0) ? HPAD : 0; r -= (r >= HPAD) ? HPAD : 0;
            bool rok = valid && (r < IMG);
#pragma unroll
            for (int i = 0; i < 4; i++) {
                int s = wp * 16 + px0 + i - dxs[c];
                s += (s < 0) ? HPAD : 0; s -= (s >= HPAD) ? HPAD : 0;
                float v = 0.0f;
                if (rok && s < IMG) v = x[((size_t)b * IMG + r) * IMG + s];
                As[lc + i][lr] = v;
            }
        }
        // load W tile
        {
            int gn = nb * 64 + lr;
            const float* wp_ = W + (size_t)gn * K + kt * 16 + lc;
#pragma unroll
            for (int i = 0; i < 4; i++) Ws[lc + i][lr] = wp_[i];
        }
        __syncthreads();
#pragma unroll
        for (int k = 0; k < 16; k++) {
            float a0 = As[k][tm0], a1 = As[k][tm0 + 1], a2 = As[k][tm0 + 2], a3 = As[k][tm0 + 3];
            float b0 = Ws[k][tn0], b1 = Ws[k][tn0 + 1], b2 = Ws[k][tn0 + 2], b3 = Ws[k][tn0 + 3];
            acc[0][0] += a0 * b0; acc[0][1] += a0 * b1; acc[0][2] += a0 * b2; acc[0][3] += a0 * b3;
            acc[1][0] += a1 * b0; acc[1][1] += a1 * b1; acc[1][2] += a1 * b2; acc[1][3] += a1 * b3;
            acc[2][0] += a2 * b0; acc[2][1] += a2 * b1; acc[2][2] += a2 * b2; acc[2][3] += a2 * b3;
            acc[3][0] += a3 * b0; acc[3][1] += a3 * b1; acc[3][2] += a3 * b2; acc[3][3] += a3 * b3;
        }
        __syncthreads();
    }

#pragma unroll
    for (int i = 0; i < 4; i++) {
        int gm2 = mb * 64 + tm0 + i;
        if (gm2 >= M) continue;
#pragma unroll
        for (int j = 0; j < 4; j++) {
            int gn = nb * 64 + tn0 + j;
            float v = acc[i][j] + bias[gn] + posemb[(size_t)(gm2 % NTOK) * N + gn];
            C[(size_t)gm2 * N + gn] = v;
        }
    }
}

// ---------------------------------------------------------------------------
// Generic GEMM: C[M,N] = A[M,K] @ W[N,K]^T  (+bias)(+gelu)(+resid). fp32.
// 64x64 tile, BK=16, 256 threads, 4x4 accum per thread.
// ---------------------------------------------------------------------------
__global__ __launch_bounds__(256) void gemm_kernel(
    const float* __restrict__ A, const float* __restrict__ W,
    const float* __restrict__ bias, const float* __restrict__ resid,
    float* __restrict__ C, int M, int N, int K, int act) {
    __shared__ float As[16][68];
    __shared__ float Ws[16][68];
    const int tid = threadIdx.x;
    const int nb = blockIdx.x, mb = blockIdx.y;
    const int lr = tid >> 2;
    const int lc = (tid & 3) * 4;
    const int tm0 = (tid >> 4) * 4;
    const int tn0 = (tid & 15) * 4;
    float acc[4][4];
#pragma unroll
    for (int i = 0; i < 4; i++)
#pragma unroll
        for (int j = 0; j < 4; j++) acc[i][j] = 0.0f;

    const int ktiles = K >> 4;
    for (int kt = 0; kt < ktiles; kt++) {
        {
            int gm = mb * 64 + lr;
            if (gm < M) {
                const float* ap = A + (size_t)gm * K + kt * 16 + lc;
#pragma unroll
                for (int i = 0; i < 4; i++) As[lc + i][lr] = ap[i];
            } else {
#pragma unroll
                for (int i = 0; i < 4; i++) As[lc + i][lr] = 0.0f;
            }
        }
        {
            int gn = nb * 64 + lr;
            const float* wp = W + (size_t)gn * K + kt * 16 + lc;
#pragma unroll
            for (int i = 0; i < 4; i++) Ws[lc + i][lr] = wp[i];
        }
        __syncthreads();
#pragma unroll
        for (int k = 0; k < 16; k++) {
            float a0 = As[k][tm0], a1 = As[k][tm0 + 1], a2 = As[k][tm0 + 2], a3 = As[k][tm0 + 3];
            float b0 = Ws[k][tn0], b1 = Ws[k][tn0 + 1], b2 = Ws[k][tn0 + 2], b3 = Ws[k][tn0 + 3];
            acc[0][0] += a0 * b0; acc[0][1] += a0 * b1; acc[0][2] += a0 * b2; acc[0][3] += a0 * b3;
            acc[1][0] += a1 * b0; acc[1][1] += a1 * b1; acc[1][2] += a1 * b2; acc[1][3] += a1 * b3;
            acc[2][0] += a2 * b0; acc[2][1] += a2 * b1; acc[2][2] += a2 * b2; acc[2][3] += a2 * b3;
            acc[3][0] += a3 * b0; acc[3][1] += a3 * b1; acc[3][2] += a3 * b2; acc[3][3] += a3 * b3;
        }
        __syncthreads();
    }

#pragma unroll
    for (int i = 0; i < 4; i++) {
        int gm = mb * 64 + tm0 + i;
        if (gm >= M) continue;
#pragma unroll
        for (int j = 0; j < 4; j++) {
            int gn = nb * 64 + tn0 + j;
            float v = acc[i][j];
            if (bias) v += bias[gn];
            if (act == 1) v = 0.5f * v * (1.0f + erff(v * 0.70710678118654752f));
            if (resid) v += resid[(size_t)gm * N + gn];
            C[(size_t)gm * N + gn] = v;
        }
    }
}

// ---------------------------------------------------------------------------
// LayerNorm over last dim (256). One block (256 threads) per row.
// ---------------------------------------------------------------------------
__global__ __launch_bounds__(256) void ln_kernel(const float* __restrict__ in,
                                                 const float* __restrict__ w,
                                                 const float* __restrict__ b,
                                                 float* __restrict__ out) {
    __shared__ float red[256];
    __shared__ float red2[256];
    const int tid = threadIdx.x;
    const size_t row = blockIdx.x;
    float x = in[row * DIM + tid];
    red[tid] = x;
    red2[tid] = x * x;
    __syncthreads();
    for (int s = 128; s > 0; s >>= 1) {
        if (tid < s) { red[tid] += red[tid + s]; red2[tid] += red2[tid + s]; }
        __syncthreads();
    }
    float mean = red[0] * (1.0f / DIM);
    float var = red2[0] * (1.0f / DIM) - mean * mean;
    float rstd = rsqrtf(var + 1e-5f);
    out[row * DIM + tid] = (x - mean) * rstd * w[tid] + b[tid];
}

// ---------------------------------------------------------------------------
// Attention: one block per (i, h, b). Strict lower-triangular mask (j < i).
// Row 0 -> zeros. qkv[b, n, 0:256]=q  [256:512]=k  [512:768]=v, head h at +h*32.
// ---------------------------------------------------------------------------
__global__ __launch_bounds__(256) void attn_kernel(const float* __restrict__ qkv,
                                                   const float* __restrict__ scale,
                                                   float* __restrict__ out) {
    __shared__ float probs[NTOK];
    __shared__ float qs[DH];
    __shared__ float red[256];
    __shared__ float pv[8][DH + 1];
    const int i = blockIdx.x, h = blockIdx.y, b = blockIdx.z;
    const int tid = threadIdx.x;
    const float* base = qkv + (size_t)b * NTOK * 768;
    if (tid < DH) qs[tid] = base[(size_t)i * 768 + h * DH + tid];
    __syncthreads();
    const float sc = scale[h];

    float lmax = -INFINITY;
    for (int j = tid; j < i; j += 256) {
        const float* krow = base + (size_t)j * 768 + 256 + h * DH;
        float dot = 0.0f;
#pragma unroll
        for (int d = 0; d < DH; d++) dot += qs[d] * krow[d];
        dot *= sc;
        probs[j] = dot;
        lmax = fmaxf(lmax, dot);
    }
    red[tid] = lmax;
    __syncthreads();
    for (int s = 128; s > 0; s >>= 1) {
        if (tid < s) red[tid] = fmaxf(red[tid], red[tid + s]);
        __syncthreads();
    }
    const float m = red[0];
    __syncthreads();

    float lsum = 0.0f;
    for (int j = tid; j < i; j += 256) {
        float p = expf(probs[j] - m);
        probs[j] = p;
        lsum += p;
    }
    red[tid] = lsum;
    __syncthreads();
    for (int s = 128; s > 0; s >>= 1) {
        if (tid < s) red[tid] += red[tid + s];
        __syncthreads();
    }
    const float l = red[0];
    const float inv = (i > 0 && l > 0.0f) ? 1.0f / l : 0.0f;
    __syncthreads();

    const int d = tid & (DH - 1);
    const int g = tid >> 5;   // 0..7
    float acc = 0.0f;
    for (int j = g; j < i; j += 8) {
        const float* vrow = base + (size_t)j * 768 + 512 + h * DH;
        acc += probs[j] * vrow[d];
    }
    pv[g][d] = acc;
    __syncthreads();
    if (tid < DH) {
        float s = 0.0f;
#pragma unroll
        for (int g2 = 0; g2 < 8; g2++) s += pv[g2][tid];
        out[((size_t)b * NTOK + i) * DIM + h * DH + tid] = s * inv;
    }
}

// ---------------------------------------------------------------------------
// Scatter pix [B, N, 256] -> out image [B, 1, 457, 457] (crop 464->457)
// ---------------------------------------------------------------------------
__global__ __launch_bounds__(256) void scatter_kernel(const float* __restrict__ pix,
                                                      float* __restrict__ out) {
    const size_t total = (size_t)BATCH * IMG * IMG;
    size_t idx = (size_t)blockIdx.x * 256 + threadIdx.x;
    if (idx >= total) return;
    int b = (int)(idx / ((size_t)IMG * IMG));
    int rem = (int)(idx % ((size_t)IMG * IMG));
    int r = rem / IMG, col = rem % IMG;
    int hp = r >> 4, py = r & 15;
    int wp = col >> 4, px = col & 15;
    out[idx] = pix[((size_t)b * NTOK + hp * 29 + wp) * DIM + py * 16 + px];
}

// ---------------------------------------------------------------------------
extern "C" void kernel_launch(void* const* d_in, const int* in_sizes, int n_in,
                              void* d_out, int out_size, void* d_ws, size_t ws_size,
                              hipStream_t stream) {
    const float* x     = (const float*)d_in[0];
    const float* pos   = (const float*)d_in[1];
    const float* sptw  = (const float*)d_in[2];
    const float* sptb  = (const float*)d_in[3];
    const float* ln1w  = (const float*)d_in[4];
    const float* ln1b  = (const float*)d_in[5];
    const float* scale = (const float*)d_in[6];
    const float* wqkv  = (const float*)d_in[7];
    const float* wout  = (const float*)d_in[8];
    const float* bout  = (const float*)d_in[9];
    const float* ln2w  = (const float*)d_in[10];
    const float* ln2b  = (const float*)d_in[11];
    const float* ff1w  = (const float*)d_in[12];
    const float* ff1b  = (const float*)d_in[13];
    const float* ff2w  = (const float*)d_in[14];
    const float* ff2b  = (const float*)d_in[15];
    const float* pixw  = (const float*)d_in[16];
    const float* pixb  = (const float*)d_in[17];
    float* out = (float*)d_out;

    const size_t NT = (size_t)ROWS * DIM;       // 1,722,368
    float* t   = (float*)d_ws;
    float* tn  = t + NT;
    float* ao  = tn + NT;
    float* big = ao + NT;                        // qkv (ROWS*768) / ff-h (ROWS*1024)
    float* qkv = big;
    float* ffh = big;

    // 1. SPT projection (fused tokenize gather) + bias + pos_emb -> t
    {
        dim3 grid(DIM / 64, (ROWS + 63) / 64);
        spt_gemm_kernel<<<grid, 256, 0, stream>>>(x, sptw, sptb, pos, t);
    }

    for (int d = 0; d < 3; d++) {
        // LN1
        ln_kernel<<<ROWS, 256, 0, stream>>>(t, ln1w + d * DIM, ln1b + d * DIM, tn);
        // QKV
        {
            dim3 grid(768 / 64, (ROWS + 63) / 64);
            gemm_kernel<<<grid, 256, 0, stream>>>(tn, wqkv + (size_t)d * 768 * DIM,
                                                  nullptr, nullptr, qkv,
                                                  ROWS, 768, DIM, 0);
        }
        // attention
        {
            dim3 grid(NTOK, HEADS, BATCH);
            attn_kernel<<<grid, 256, 0, stream>>>(qkv, scale + d * HEADS, ao);
        }
        // out proj + bias + residual -> t
        {
            dim3 grid(DIM / 64, (ROWS + 63) / 64);
            gemm_kernel<<<grid, 256, 0, stream>>>(ao, wout + (size_t)d * DIM * DIM,
                                                  bout + d * DIM, t, t,
                                                  ROWS, DIM, DIM, 0);
        }
        // LN2
        ln_kernel<<<ROWS, 256, 0, stream>>>(t, ln2w + d * DIM, ln2b + d * DIM, tn);
        // FF1 + gelu
        {
            dim3 grid(1024 / 64, (ROWS + 63) / 64);
            gemm_kernel<<<grid, 256, 0, stream>>>(tn, ff1w + (size_t)d * 1024 * DIM,
                                                  ff1b + d * 1024, nullptr, ffh,
                                                  ROWS, 1024, DIM, 1);
        }
        // FF2 + bias + residual -> t
        {
            dim3 grid(DIM / 64, (ROWS + 63) / 64);
            gemm_kernel<<<grid, 256, 0, stream>>>(ffh, ff2w + (size_t)d * DIM * 1024,
                                                  ff2b + d * DIM, t, t,
                                                  ROWS, DIM, 1024, 0);
        }
    }

    // pix projection -> tn
    {
        dim3 grid(DIM / 64, (ROWS + 63) / 64);
        gemm_kernel<<<grid, 256, 0, stream>>>(t, pixw, pixb, nullptr, tn,
                                              ROWS, DIM, DIM, 0);
    }
    // scatter to output image
    {
        size_t total = (size_t)BATCH * IMG * IMG;
        scatter_kernel<<<dim3((unsigned)((total + 255) / 256)), 256, 0, stream>>>(tn, out);
    }
}

// Round 3
// 1250.761 us; speedup vs baseline: 2.0885x; 2.0885x over previous
//
#include <hip/hip_runtime.h>
#include <hip/hip_bf16.h>
#include <math.h>

#define NTOK 841          // 29*29 patches
#define BATCH 8
#define DIM 256
#define HEADS 8
#define DH 32
#define IMG 457
#define HPAD 464
#define ROWS (BATCH * NTOK)   // 6728

// ---------------------------------------------------------------------------
// SPT GEMM with fused tokenize gather:
// C[M=ROWS, N=256] = tok[M, K=1280] @ W[N,K]^T + bias + pos_emb
// ---------------------------------------------------------------------------
__global__ __launch_bounds__(256) void spt_gemm_kernel(
    const float* __restrict__ x, const float* __restrict__ W,
    const float* __restrict__ bias, const float* __restrict__ posemb,
    float* __restrict__ C) {
    __shared__ float As[16][68];
    __shared__ float Ws[16][68];
    const int tid = threadIdx.x;
    const int nb = blockIdx.x, mb = blockIdx.y;
    const int lr = tid >> 2;            // 0..63
    const int lc = (tid & 3) * 4;       // 0,4,8,12
    const int tm0 = (tid >> 4) * 4;
    const int tn0 = (tid & 15) * 4;
    const int M = ROWS, N = DIM, K = 1280;

    const int gm = mb * 64 + lr;
    const bool valid = gm < M;
    int b = 0, hp = 0, wp = 0;
    if (valid) {
        b = gm / NTOK;
        int n = gm - b * NTOK;
        hp = n / 29;
        wp = n - hp * 29;
    }
    const int dxs[5] = {0, -8, 8, -8, 8};
    const int dys[5] = {0, -8, -8, 8, 8};

    float acc[4][4];
#pragma unroll
    for (int i = 0; i < 4; i++)
#pragma unroll
        for (int j = 0; j < 4; j++) acc[i][j] = 0.0f;

    for (int kt = 0; kt < K / 16; kt++) {
        {
            int k0 = kt * 16 + lc;
            int c = k0 >> 8;
            int py = (k0 >> 4) & 15;
            int px0 = k0 & 15;
            int r = hp * 16 + py - dys[c];
            r += (r < 0) ? HPAD : 0; r -= (r >= HPAD) ? HPAD : 0;
            bool rok = valid && (r < IMG);
#pragma unroll
            for (int i = 0; i < 4; i++) {
                int s = wp * 16 + px0 + i - dxs[c];
                s += (s < 0) ? HPAD : 0; s -= (s >= HPAD) ? HPAD : 0;
                float v = 0.0f;
                if (rok && s < IMG) v = x[((size_t)b * IMG + r) * IMG + s];
                As[lc + i][lr] = v;
            }
        }
        {
            int gn = nb * 64 + lr;
            const float* wp_ = W + (size_t)gn * K + kt * 16 + lc;
#pragma unroll
            for (int i = 0; i < 4; i++) Ws[lc + i][lr] = wp_[i];
        }
        __syncthreads();
#pragma unroll
        for (int k = 0; k < 16; k++) {
            float a0 = As[k][tm0], a1 = As[k][tm0 + 1], a2 = As[k][tm0 + 2], a3 = As[k][tm0 + 3];
            float b0 = Ws[k][tn0], b1 = Ws[k][tn0 + 1], b2 = Ws[k][tn0 + 2], b3 = Ws[k][tn0 + 3];
            acc[0][0] += a0 * b0; acc[0][1] += a0 * b1; acc[0][2] += a0 * b2; acc[0][3] += a0 * b3;
            acc[1][0] += a1 * b0; acc[1][1] += a1 * b1; acc[1][2] += a1 * b2; acc[1][3] += a1 * b3;
            acc[2][0] += a2 * b0; acc[2][1] += a2 * b1; acc[2][2] += a2 * b2; acc[2][3] += a2 * b3;
            acc[3][0] += a3 * b0; acc[3][1] += a3 * b1; acc[3][2] += a3 * b2; acc[3][3] += a3 * b3;
        }
        __syncthreads();
    }

#pragma unroll
    for (int i = 0; i < 4; i++) {
        int gm2 = mb * 64 + tm0 + i;
        if (gm2 >= M) continue;
#pragma unroll
        for (int j = 0; j < 4; j++) {
            int gn = nb * 64 + tn0 + j;
            float v = acc[i][j] + bias[gn] + posemb[(size_t)(gm2 % NTOK) * N + gn];
            C[(size_t)gm2 * N + gn] = v;
        }
    }
}

// ---------------------------------------------------------------------------
// Generic GEMM: C[M,N] = A[M,K] @ W[N,K]^T  (+bias)(+gelu)(+resid). fp32.
// ---------------------------------------------------------------------------
__global__ __launch_bounds__(256) void gemm_kernel(
    const float* __restrict__ A, const float* __restrict__ W,
    const float* __restrict__ bias, const float* __restrict__ resid,
    float* __restrict__ C, int M, int N, int K, int act) {
    __shared__ float As[16][68];
    __shared__ float Ws[16][68];
    const int tid = threadIdx.x;
    const int nb = blockIdx.x, mb = blockIdx.y;
    const int lr = tid >> 2;
    const int lc = (tid & 3) * 4;
    const int tm0 = (tid >> 4) * 4;
    const int tn0 = (tid & 15) * 4;
    float acc[4][4];
#pragma unroll
    for (int i = 0; i < 4; i++)
#pragma unroll
        for (int j = 0; j < 4; j++) acc[i][j] = 0.0f;

    const int ktiles = K >> 4;
    for (int kt = 0; kt < ktiles; kt++) {
        {
            int gm = mb * 64 + lr;
            if (gm < M) {
                const float* ap = A + (size_t)gm * K + kt * 16 + lc;
#pragma unroll
                for (int i = 0; i < 4; i++) As[lc + i][lr] = ap[i];
            } else {
#pragma unroll
                for (int i = 0; i < 4; i++) As[lc + i][lr] = 0.0f;
            }
        }
        {
            int gn = nb * 64 + lr;
            const float* wp = W + (size_t)gn * K + kt * 16 + lc;
#pragma unroll
            for (int i = 0; i < 4; i++) Ws[lc + i][lr] = wp[i];
        }
        __syncthreads();
#pragma unroll
        for (int k = 0; k < 16; k++) {
            float a0 = As[k][tm0], a1 = As[k][tm0 + 1], a2 = As[k][tm0 + 2], a3 = As[k][tm0 + 3];
            float b0 = Ws[k][tn0], b1 = Ws[k][tn0 + 1], b2 = Ws[k][tn0 + 2], b3 = Ws[k][tn0 + 3];
            acc[0][0] += a0 * b0; acc[0][1] += a0 * b1; acc[0][2] += a0 * b2; acc[0][3] += a0 * b3;
            acc[1][0] += a1 * b0; acc[1][1] += a1 * b1; acc[1][2] += a1 * b2; acc[1][3] += a1 * b3;
            acc[2][0] += a2 * b0; acc[2][1] += a2 * b1; acc[2][2] += a2 * b2; acc[2][3] += a2 * b3;
            acc[3][0] += a3 * b0; acc[3][1] += a3 * b1; acc[3][2] += a3 * b2; acc[3][3] += a3 * b3;
        }
        __syncthreads();
    }

#pragma unroll
    for (int i = 0; i < 4; i++) {
        int gm = mb * 64 + tm0 + i;
        if (gm >= M) continue;
#pragma unroll
        for (int j = 0; j < 4; j++) {
            int gn = nb * 64 + tn0 + j;
            float v = acc[i][j];
            if (bias) v += bias[gn];
            if (act == 1) v = 0.5f * v * (1.0f + erff(v * 0.70710678118654752f));
            if (resid) v += resid[(size_t)gm * N + gn];
            C[(size_t)gm * N + gn] = v;
        }
    }
}

// ---------------------------------------------------------------------------
// LayerNorm over last dim (256). One block (256 threads) per row.
// ---------------------------------------------------------------------------
__global__ __launch_bounds__(256) void ln_kernel(const float* __restrict__ in,
                                                 const float* __restrict__ w,
                                                 const float* __restrict__ b,
                                                 float* __restrict__ out) {
    __shared__ float red[256];
    __shared__ float red2[256];
    const int tid = threadIdx.x;
    const size_t row = blockIdx.x;
    float x = in[row * DIM + tid];
    red[tid] = x;
    red2[tid] = x * x;
    __syncthreads();
    for (int s = 128; s > 0; s >>= 1) {
        if (tid < s) { red[tid] += red[tid + s]; red2[tid] += red2[tid + s]; }
        __syncthreads();
    }
    float mean = red[0] * (1.0f / DIM);
    float var = red2[0] * (1.0f / DIM) - mean * mean;
    float rstd = rsqrtf(var + 1e-5f);
    out[row * DIM + tid] = (x - mean) * rstd * w[tid] + b[tid];
}

// ---------------------------------------------------------------------------
// Flash-tile attention. One block per (i-tile of 64 rows, head, batch).
// Strict causal mask j < i; row 0 -> zeros.
// qkv[b, n, 0:256]=q [256:512]=k [512:768]=v, head h at +h*32.
// 64x64 S-tiles, online softmax, PV via LDS round-trip (Ps).
// ---------------------------------------------------------------------------
__global__ __launch_bounds__(256) void attn_flash_kernel(
    const float* __restrict__ qkv, const float* __restrict__ scale,
    float* __restrict__ out) {
    __shared__ float Qs[32][68];   // [d][i]
    __shared__ float Ks[32][68];   // [d][j]
    __shared__ float Vs[64][36];   // [j][d]
    __shared__ float Ps[64][68];   // [i][j]

    const int tid = threadIdx.x;
    const int bh = blockIdx.x;
    const int b = bh >> 3, h = bh & 7;
    const int it = (int)gridDim.y - 1 - (int)blockIdx.y;   // longest blocks first
    const int i0 = it * 64;
    const float sc = scale[h];
    const float* base = qkv + (size_t)b * NTOK * 768;

    const int tm0 = (tid >> 4) * 4;        // 4 i-rows per thread
    const int tn0 = (tid & 15) * 4;        // 4 j-cols per thread (S phase)
    const int c2 = (tid & 15) * 2;         // 2 dh-cols per thread (PV phase)

    // stage Q tile: Qs[d][r] for r=0..63
    {
        int r = tid >> 3;                  // 0..31
        int c4 = (tid & 7) * 4;            // d
#pragma unroll
        for (int r0 = 0; r0 < 64; r0 += 32) {
            int gi = i0 + r0 + r;
            float4 q = make_float4(0.f, 0.f, 0.f, 0.f);
            if (gi < NTOK)
                q = *(const float4*)&base[(size_t)gi * 768 + h * DH + c4];
            Qs[c4 + 0][r0 + r] = q.x;
            Qs[c4 + 1][r0 + r] = q.y;
            Qs[c4 + 2][r0 + r] = q.z;
            Qs[c4 + 3][r0 + r] = q.w;
        }
    }

    float m[4], l[4], O[4][2];
#pragma unroll
    for (int ii = 0; ii < 4; ii++) {
        m[ii] = -1e30f; l[ii] = 0.0f; O[ii][0] = 0.0f; O[ii][1] = 0.0f;
    }

    for (int jt = 0; jt <= it; jt++) {
        const int j0 = jt * 64;
        __syncthreads();   // protect Ks/Vs/Ps from previous iteration's readers
        // stage K (transposed) and V tiles
        {
            int r = tid >> 3;
            int c4 = (tid & 7) * 4;
#pragma unroll
            for (int r0 = 0; r0 < 64; r0 += 32) {
                int gj = j0 + r0 + r;
                float4 k4 = make_float4(0.f, 0.f, 0.f, 0.f);
                float4 v4 = make_float4(0.f, 0.f, 0.f, 0.f);
                if (gj < NTOK) {
                    k4 = *(const float4*)&base[(size_t)gj * 768 + 256 + h * DH + c4];
                    v4 = *(const float4*)&base[(size_t)gj * 768 + 512 + h * DH + c4];
                }
                Ks[c4 + 0][r0 + r] = k4.x;
                Ks[c4 + 1][r0 + r] = k4.y;
                Ks[c4 + 2][r0 + r] = k4.z;
                Ks[c4 + 3][r0 + r] = k4.w;
                *(float4*)&Vs[r0 + r][c4] = v4;
            }
        }
        __syncthreads();

        // S = Q K^T (64x64), 4x4 per thread
        float s[4][4];
#pragma unroll
        for (int ii = 0; ii < 4; ii++)
#pragma unroll
            for (int jj = 0; jj < 4; jj++) s[ii][jj] = 0.0f;
#pragma unroll 8
        for (int d = 0; d < 32; d++) {
            float4 aa = *(const float4*)&Qs[d][tm0];
            float4 bb = *(const float4*)&Ks[d][tn0];
            float a[4] = {aa.x, aa.y, aa.z, aa.w};
            float bv[4] = {bb.x, bb.y, bb.z, bb.w};
#pragma unroll
            for (int ii = 0; ii < 4; ii++)
#pragma unroll
                for (int jj = 0; jj < 4; jj++) s[ii][jj] += a[ii] * bv[jj];
        }

        // mask + online softmax (per i-row, reduced across the 16 lanes of the row group)
#pragma unroll
        for (int ii = 0; ii < 4; ii++) {
            const int gi = i0 + tm0 + ii;
            float mloc = -1e30f;
#pragma unroll
            for (int jj = 0; jj < 4; jj++) {
                float sv = s[ii][jj] * sc;
                bool ok = (j0 + tn0 + jj < gi) && (gi < NTOK);
                sv = ok ? sv : -1e30f;
                s[ii][jj] = sv;
                mloc = fmaxf(mloc, sv);
            }
#pragma unroll
            for (int off = 1; off < 16; off <<= 1)
                mloc = fmaxf(mloc, __shfl_xor(mloc, off));
            float mnew = fmaxf(m[ii], mloc);
            float alpha = __expf(m[ii] - mnew);   // both -1e30 -> exp(0)=1
            m[ii] = mnew;
            float lsum = 0.0f;
#pragma unroll
            for (int jj = 0; jj < 4; jj++) {
                float p = __expf(s[ii][jj] - mnew);
                s[ii][jj] = p;
                lsum += p;
            }
#pragma unroll
            for (int off = 1; off < 16; off <<= 1)
                lsum += __shfl_xor(lsum, off);
            l[ii] = l[ii] * alpha + lsum;
            O[ii][0] *= alpha;
            O[ii][1] *= alpha;
            *(float4*)&Ps[tm0 + ii][tn0] = make_float4(s[ii][0], s[ii][1], s[ii][2], s[ii][3]);
        }
        __syncthreads();

        // O += P V  (64x64 @ 64x32), rows tm0..+3, cols c2..c2+1 per thread
#pragma unroll 4
        for (int k0 = 0; k0 < 64; k0 += 4) {
#pragma unroll
            for (int u = 0; u < 4; u++) {
                float2 vv = *(const float2*)&Vs[k0 + u][c2];
#pragma unroll
                for (int ii = 0; ii < 4; ii++) {
                    float pr = Ps[tm0 + ii][k0 + u];
                    O[ii][0] += pr * vv.x;
                    O[ii][1] += pr * vv.y;
                }
            }
        }
    }

    // epilogue: normalize and store
#pragma unroll
    for (int ii = 0; ii < 4; ii++) {
        int gi = i0 + tm0 + ii;
        if (gi >= NTOK) continue;
        float iv = (gi > 0 && l[ii] > 0.0f) ? 1.0f / l[ii] : 0.0f;
        float* op = out + ((size_t)b * NTOK + gi) * DIM + h * DH + c2;
        op[0] = O[ii][0] * iv;
        op[1] = O[ii][1] * iv;
    }
}

// ---------------------------------------------------------------------------
// Scatter pix [B, N, 256] -> out image [B, 1, 457, 457] (crop 464->457)
// ---------------------------------------------------------------------------
__global__ __launch_bounds__(256) void scatter_kernel(const float* __restrict__ pix,
                                                      float* __restrict__ out) {
    const size_t total = (size_t)BATCH * IMG * IMG;
    size_t idx = (size_t)blockIdx.x * 256 + threadIdx.x;
    if (idx >= total) return;
    int b = (int)(idx / ((size_t)IMG * IMG));
    int rem = (int)(idx % ((size_t)IMG * IMG));
    int r = rem / IMG, col = rem % IMG;
    int hp = r >> 4, py = r & 15;
    int wp = col >> 4, px = col & 15;
    out[idx] = pix[((size_t)b * NTOK + hp * 29 + wp) * DIM + py * 16 + px];
}

// ---------------------------------------------------------------------------
extern "C" void kernel_launch(void* const* d_in, const int* in_sizes, int n_in,
                              void* d_out, int out_size, void* d_ws, size_t ws_size,
                              hipStream_t stream) {
    const float* x     = (const float*)d_in[0];
    const float* pos   = (const float*)d_in[1];
    const float* sptw  = (const float*)d_in[2];
    const float* sptb  = (const float*)d_in[3];
    const float* ln1w  = (const float*)d_in[4];
    const float* ln1b  = (const float*)d_in[5];
    const float* scale = (const float*)d_in[6];
    const float* wqkv  = (const float*)d_in[7];
    const float* wout  = (const float*)d_in[8];
    const float* bout  = (const float*)d_in[9];
    const float* ln2w  = (const float*)d_in[10];
    const float* ln2b  = (const float*)d_in[11];
    const float* ff1w  = (const float*)d_in[12];
    const float* ff1b  = (const float*)d_in[13];
    const float* ff2w  = (const float*)d_in[14];
    const float* ff2b  = (const float*)d_in[15];
    const float* pixw  = (const float*)d_in[16];
    const float* pixb  = (const float*)d_in[17];
    float* out = (float*)d_out;

    const size_t NT = (size_t)ROWS * DIM;       // 1,722,368
    float* t   = (float*)d_ws;
    float* tn  = t + NT;
    float* ao  = tn + NT;
    float* big = ao + NT;                        // qkv (ROWS*768) / ff-h (ROWS*1024)
    float* qkv = big;
    float* ffh = big;

    // 1. SPT projection (fused tokenize gather) + bias + pos_emb -> t
    {
        dim3 grid(DIM / 64, (ROWS + 63) / 64);
        spt_gemm_kernel<<<grid, 256, 0, stream>>>(x, sptw, sptb, pos, t);
    }

    for (int d = 0; d < 3; d++) {
        // LN1
        ln_kernel<<<ROWS, 256, 0, stream>>>(t, ln1w + d * DIM, ln1b + d * DIM, tn);
        // QKV
        {
            dim3 grid(768 / 64, (ROWS + 63) / 64);
            gemm_kernel<<<grid, 256, 0, stream>>>(tn, wqkv + (size_t)d * 768 * DIM,
                                                  nullptr, nullptr, qkv,
                                                  ROWS, 768, DIM, 0);
        }
        // flash attention
        {
            dim3 grid(BATCH * HEADS, (NTOK + 63) / 64);   // (64, 14)
            attn_flash_kernel<<<grid, 256, 0, stream>>>(qkv, scale + d * HEADS, ao);
        }
        // out proj + bias + residual -> t
        {
            dim3 grid(DIM / 64, (ROWS + 63) / 64);
            gemm_kernel<<<grid, 256, 0, stream>>>(ao, wout + (size_t)d * DIM * DIM,
                                                  bout + d * DIM, t, t,
                                                  ROWS, DIM, DIM, 0);
        }
        // LN2
        ln_kernel<<<ROWS, 256, 0, stream>>>(t, ln2w + d * DIM, ln2b + d * DIM, tn);
        // FF1 + gelu
        {
            dim3 grid(1024 / 64, (ROWS + 63) / 64);
            gemm_kernel<<<grid, 256, 0, stream>>>(tn, ff1w + (size_t)d * 1024 * DIM,
                                                  ff1b + d * 1024, nullptr, ffh,
                                                  ROWS, 1024, DIM, 1);
        }
        // FF2 + bias + residual -> t
        {
            dim3 grid(DIM / 64, (ROWS + 63) / 64);
            gemm_kernel<<<grid, 256, 0, stream>>>(ffh, ff2w + (size_t)d * DIM * 1024,
                                                  ff2b + d * DIM, t, t,
                                                  ROWS, DIM, 1024, 0);
        }
    }

    // pix projection -> tn
    {
        dim3 grid(DIM / 64, (ROWS + 63) / 64);
        gemm_kernel<<<grid, 256, 0, stream>>>(t, pixw, pixb, nullptr, tn,
                                              ROWS, DIM, DIM, 0);
    }
    // scatter to output image
    {
        size_t total = (size_t)BATCH * IMG * IMG;
        scatter_kernel<<<dim3((unsigned)((total + 255) / 256)), 256, 0, stream>>>(tn, out);
    }
}

// Round 4
// 906.520 us; speedup vs baseline: 2.8815x; 1.3797x over previous
//
#include <hip/hip_runtime.h>
#include <hip/hip_bf16.h>
#include <math.h>

typedef __hip_bfloat16 bf16;
typedef short bf16x8 __attribute__((ext_vector_type(8)));
typedef float floatx4 __attribute__((ext_vector_type(4)));

#define NTOK 841          // 29*29 patches
#define BATCH 8
#define DIM 256
#define HEADS 8
#define DH 32
#define IMG 457
#define HPAD 464
#define ROWS (BATCH * NTOK)   // 6728
#define LDA 40                // padded LDS row stride (bf16 elems) -> 80B

// weight segment offsets (elements) in the packed bf16 weight buffer
#define W_SPT   0
#define W_QKV   327680
#define W_OUT   917504
#define W_FF1   1114112
#define W_FF2   1900544
#define W_PIX   2686976
#define W_TOTAL 2752512

// ---------------------------------------------------------------------------
// Convert all weight tensors fp32 -> bf16 into one packed buffer.
// 4 elements per thread; grid covers W_TOTAL/4 = 688128 threads exactly.
// ---------------------------------------------------------------------------
__global__ __launch_bounds__(256) void wconv_kernel(
    const float* __restrict__ s_spt, const float* __restrict__ s_qkv,
    const float* __restrict__ s_out, const float* __restrict__ s_ff1,
    const float* __restrict__ s_ff2, const float* __restrict__ s_pix,
    bf16* __restrict__ dst) {
    int idx = (blockIdx.x * 256 + threadIdx.x) * 4;
    const float* src; int off;
    if      (idx < W_QKV) { src = s_spt; off = W_SPT; }
    else if (idx < W_OUT) { src = s_qkv; off = W_QKV; }
    else if (idx < W_FF1) { src = s_out; off = W_OUT; }
    else if (idx < W_FF2) { src = s_ff1; off = W_FF1; }
    else if (idx < W_PIX) { src = s_ff2; off = W_FF2; }
    else                  { src = s_pix; off = W_PIX; }
    float4 v = *(const float4*)(src + (idx - off));
    union { ushort4 u; bf16 h[4]; } pk;
    pk.h[0] = __float2bfloat16(v.x);
    pk.h[1] = __float2bfloat16(v.y);
    pk.h[2] = __float2bfloat16(v.z);
    pk.h[3] = __float2bfloat16(v.w);
    *(ushort4*)(dst + idx) = pk.u;
}

// ---------------------------------------------------------------------------
// Tokenize gather -> bf16 tok[ROWS][1280], k=(c,py,px).
// 4 consecutive px per thread; 2,152,960 threads exactly (8410 blocks).
// ---------------------------------------------------------------------------
__global__ __launch_bounds__(256) void tokenize_kernel(const float* __restrict__ x,
                                                       bf16* __restrict__ tok) {
    int idx = blockIdx.x * 256 + threadIdx.x;
    int gm = idx / 320;
    int k4 = (idx - gm * 320) * 4;
    int b = gm / NTOK;
    int n = gm - b * NTOK;
    int hp = n / 29, wp = n - (n / 29) * 29;
    int c = k4 >> 8;
    int py = (k4 >> 4) & 15;
    int px0 = k4 & 15;
    const int dxs[5] = {0, -8, 8, -8, 8};
    const int dys[5] = {0, -8, -8, 8, 8};
    int r = hp * 16 + py - dys[c];
    r += (r < 0) ? HPAD : 0; r -= (r >= HPAD) ? HPAD : 0;
    bool rok = (r < IMG);
    union { ushort4 u; bf16 h[4]; } pk;
#pragma unroll
    for (int i = 0; i < 4; i++) {
        int s = wp * 16 + px0 + i - dxs[c];
        s += (s < 0) ? HPAD : 0; s -= (s >= HPAD) ? HPAD : 0;
        float v = 0.0f;
        if (rok && s < IMG) v = x[((size_t)b * IMG + r) * IMG + s];
        pk.h[i] = __float2bfloat16(v);
    }
    *(ushort4*)(tok + (size_t)gm * 1280 + k4) = pk.u;
}

// ---------------------------------------------------------------------------
// MFMA GEMM: C[M,N] = A[M,K]bf16 @ W[N,K]bf16^T, fp32 accum.
// 128x128 block tile, BK=32, 4 waves (2x2 of 64x64), 16x16x32 MFMA.
// Epilogue: +bias, gelu, +posemb, +resid; writes fp32 Cf and/or bf16 Cb.
// N % 128 == 0 and K % 32 == 0 required; M bounds-checked.
// ---------------------------------------------------------------------------
__global__ __launch_bounds__(256) void mfma_gemm_kernel(
    const bf16* __restrict__ A, const bf16* __restrict__ W,
    const float* __restrict__ bias, const float* __restrict__ resid,
    const float* __restrict__ posemb, float* __restrict__ Cf,
    bf16* __restrict__ Cb, int M, int N, int K, int act) {
    __shared__ bf16 As[128 * LDA];
    __shared__ bf16 Bs[128 * LDA];
    const int tid = threadIdx.x;
    const int m0 = blockIdx.y * 128, n0 = blockIdx.x * 128;
    const int w = tid >> 6, lane = tid & 63;
    const int wm = (w >> 1) * 64, wn = (w & 1) * 64;
    const int li = lane & 15, quad = lane >> 4;

    floatx4 acc[4][4] = {};

    for (int k0 = 0; k0 < K; k0 += 32) {
        // stage A and W tiles: 512 chunks of 16B each per tile, 2 per thread
#pragma unroll
        for (int i = 0; i < 2; i++) {
            int c = tid + i * 256;
            int row = c >> 2, ko = (c & 3) << 3;   // ko in bf16 elems
            int gm = m0 + row;
            float4 av = make_float4(0.f, 0.f, 0.f, 0.f);
            if (gm < M) av = *(const float4*)(A + (size_t)gm * K + k0 + ko);
            *(float4*)&As[row * LDA + ko] = av;
            int gn = n0 + row;
            float4 wv = *(const float4*)(W + (size_t)gn * K + k0 + ko);
            *(float4*)&Bs[row * LDA + ko] = wv;
        }
        __syncthreads();
        bf16x8 af[4], bfr[4];
#pragma unroll
        for (int t = 0; t < 4; t++) {
            af[t]  = *(const bf16x8*)&As[(wm + t * 16 + li) * LDA + quad * 8];
            bfr[t] = *(const bf16x8*)&Bs[(wn + t * 16 + li) * LDA + quad * 8];
        }
#pragma unroll
        for (int ti = 0; ti < 4; ti++)
#pragma unroll
            for (int tj = 0; tj < 4; tj++)
                acc[ti][tj] = __builtin_amdgcn_mfma_f32_16x16x32_bf16(
                    af[ti], bfr[tj], acc[ti][tj], 0, 0, 0);
        __syncthreads();
    }

    // epilogue: C row = quad*4 + reg, col = lane&15 (verified m89/m91 layout)
#pragma unroll
    for (int ti = 0; ti < 4; ti++) {
#pragma unroll
        for (int r = 0; r < 4; r++) {
            int gm = m0 + wm + ti * 16 + quad * 4 + r;
            if (gm >= M) continue;
#pragma unroll
            for (int tj = 0; tj < 4; tj++) {
                int gn = n0 + wn + tj * 16 + li;
                float v = acc[ti][tj][r];
                if (bias) v += bias[gn];
                if (act) v = 0.5f * v * (1.0f + erff(v * 0.70710678118654752f));
                if (posemb) v += posemb[(size_t)(gm % NTOK) * N + gn];
                if (resid) v += resid[(size_t)gm * N + gn];
                if (Cf) Cf[(size_t)gm * N + gn] = v;
                if (Cb) Cb[(size_t)gm * N + gn] = __float2bfloat16(v);
            }
        }
    }
}

// ---------------------------------------------------------------------------
// LayerNorm over last dim (256). One block per row. fp32 in -> bf16 out.
// ---------------------------------------------------------------------------
__global__ __launch_bounds__(256) void ln_kernel(const float* __restrict__ in,
                                                 const float* __restrict__ w,
                                                 const float* __restrict__ b,
                                                 bf16* __restrict__ out) {
    __shared__ float red[256];
    __shared__ float red2[256];
    const int tid = threadIdx.x;
    const size_t row = blockIdx.x;
    float x = in[row * DIM + tid];
    red[tid] = x;
    red2[tid] = x * x;
    __syncthreads();
    for (int s = 128; s > 0; s >>= 1) {
        if (tid < s) { red[tid] += red[tid + s]; red2[tid] += red2[tid + s]; }
        __syncthreads();
    }
    float mean = red[0] * (1.0f / DIM);
    float var = red2[0] * (1.0f / DIM) - mean * mean;
    float rstd = rsqrtf(var + 1e-5f);
    out[row * DIM + tid] = __float2bfloat16((x - mean) * rstd * w[tid] + b[tid]);
}

// ---------------------------------------------------------------------------
// Flash-tile attention (fp32 compute). One block per (i-tile 64, head, batch).
// Strict causal mask j < i; row 0 -> zeros. Output bf16.
// ---------------------------------------------------------------------------
__global__ __launch_bounds__(256) void attn_flash_kernel(
    const float* __restrict__ qkv, const float* __restrict__ scale,
    bf16* __restrict__ out) {
    __shared__ float Qs[32][68];   // [d][i]
    __shared__ float Ks[32][68];   // [d][j]
    __shared__ float Vs[64][36];   // [j][d]
    __shared__ float Ps[64][68];   // [i][j]

    const int tid = threadIdx.x;
    const int bh = blockIdx.x;
    const int b = bh >> 3, h = bh & 7;
    const int it = (int)gridDim.y - 1 - (int)blockIdx.y;
    const int i0 = it * 64;
    const float sc = scale[h];
    const float* base = qkv + (size_t)b * NTOK * 768;

    const int tm0 = (tid >> 4) * 4;
    const int tn0 = (tid & 15) * 4;
    const int c2 = (tid & 15) * 2;

    {
        int r = tid >> 3;
        int c4 = (tid & 7) * 4;
#pragma unroll
        for (int r0 = 0; r0 < 64; r0 += 32) {
            int gi = i0 + r0 + r;
            float4 q = make_float4(0.f, 0.f, 0.f, 0.f);
            if (gi < NTOK)
                q = *(const float4*)&base[(size_t)gi * 768 + h * DH + c4];
            Qs[c4 + 0][r0 + r] = q.x;
            Qs[c4 + 1][r0 + r] = q.y;
            Qs[c4 + 2][r0 + r] = q.z;
            Qs[c4 + 3][r0 + r] = q.w;
        }
    }

    float m[4], l[4], O[4][2];
#pragma unroll
    for (int ii = 0; ii < 4; ii++) {
        m[ii] = -1e30f; l[ii] = 0.0f; O[ii][0] = 0.0f; O[ii][1] = 0.0f;
    }

    for (int jt = 0; jt <= it; jt++) {
        const int j0 = jt * 64;
        __syncthreads();
        {
            int r = tid >> 3;
            int c4 = (tid & 7) * 4;
#pragma unroll
            for (int r0 = 0; r0 < 64; r0 += 32) {
                int gj = j0 + r0 + r;
                float4 k4 = make_float4(0.f, 0.f, 0.f, 0.f);
                float4 v4 = make_float4(0.f, 0.f, 0.f, 0.f);
                if (gj < NTOK) {
                    k4 = *(const float4*)&base[(size_t)gj * 768 + 256 + h * DH + c4];
                    v4 = *(const float4*)&base[(size_t)gj * 768 + 512 + h * DH + c4];
                }
                Ks[c4 + 0][r0 + r] = k4.x;
                Ks[c4 + 1][r0 + r] = k4.y;
                Ks[c4 + 2][r0 + r] = k4.z;
                Ks[c4 + 3][r0 + r] = k4.w;
                *(float4*)&Vs[r0 + r][c4] = v4;
            }
        }
        __syncthreads();

        float s[4][4];
#pragma unroll
        for (int ii = 0; ii < 4; ii++)
#pragma unroll
            for (int jj = 0; jj < 4; jj++) s[ii][jj] = 0.0f;
#pragma unroll 8
        for (int d = 0; d < 32; d++) {
            float4 aa = *(const float4*)&Qs[d][tm0];
            float4 bb = *(const float4*)&Ks[d][tn0];
            float a[4] = {aa.x, aa.y, aa.z, aa.w};
            float bv[4] = {bb.x, bb.y, bb.z, bb.w};
#pragma unroll
            for (int ii = 0; ii < 4; ii++)
#pragma unroll
                for (int jj = 0; jj < 4; jj++) s[ii][jj] += a[ii] * bv[jj];
        }

#pragma unroll
        for (int ii = 0; ii < 4; ii++) {
            const int gi = i0 + tm0 + ii;
            float mloc = -1e30f;
#pragma unroll
            for (int jj = 0; jj < 4; jj++) {
                float sv = s[ii][jj] * sc;
                bool ok = (j0 + tn0 + jj < gi) && (gi < NTOK);
                sv = ok ? sv : -1e30f;
                s[ii][jj] = sv;
                mloc = fmaxf(mloc, sv);
            }
#pragma unroll
            for (int off = 1; off < 16; off <<= 1)
                mloc = fmaxf(mloc, __shfl_xor(mloc, off));
            float mnew = fmaxf(m[ii], mloc);
            float alpha = __expf(m[ii] - mnew);
            m[ii] = mnew;
            float lsum = 0.0f;
#pragma unroll
            for (int jj = 0; jj < 4; jj++) {
                float p = __expf(s[ii][jj] - mnew);
                s[ii][jj] = p;
                lsum += p;
            }
#pragma unroll
            for (int off = 1; off < 16; off <<= 1)
                lsum += __shfl_xor(lsum, off);
            l[ii] = l[ii] * alpha + lsum;
            O[ii][0] *= alpha;
            O[ii][1] *= alpha;
            *(float4*)&Ps[tm0 + ii][tn0] = make_float4(s[ii][0], s[ii][1], s[ii][2], s[ii][3]);
        }
        __syncthreads();

#pragma unroll 4
        for (int k0 = 0; k0 < 64; k0 += 4) {
#pragma unroll
            for (int u = 0; u < 4; u++) {
                float2 vv = *(const float2*)&Vs[k0 + u][c2];
#pragma unroll
                for (int ii = 0; ii < 4; ii++) {
                    float pr = Ps[tm0 + ii][k0 + u];
                    O[ii][0] += pr * vv.x;
                    O[ii][1] += pr * vv.y;
                }
            }
        }
    }

#pragma unroll
    for (int ii = 0; ii < 4; ii++) {
        int gi = i0 + tm0 + ii;
        if (gi >= NTOK) continue;
        float iv = (gi > 0 && l[ii] > 0.0f) ? 1.0f / l[ii] : 0.0f;
        bf16* op = out + ((size_t)b * NTOK + gi) * DIM + h * DH + c2;
        op[0] = __float2bfloat16(O[ii][0] * iv);
        op[1] = __float2bfloat16(O[ii][1] * iv);
    }
}

// ---------------------------------------------------------------------------
// Scatter pix [B, N, 256] fp32 -> out image [B,1,457,457] fp32 (crop)
// ---------------------------------------------------------------------------
__global__ __launch_bounds__(256) void scatter_kernel(const float* __restrict__ pix,
                                                      float* __restrict__ out) {
    const size_t total = (size_t)BATCH * IMG * IMG;
    size_t idx = (size_t)blockIdx.x * 256 + threadIdx.x;
    if (idx >= total) return;
    int b = (int)(idx / ((size_t)IMG * IMG));
    int rem = (int)(idx % ((size_t)IMG * IMG));
    int r = rem / IMG, col = rem % IMG;
    int hp = r >> 4, py = r & 15;
    int wp = col >> 4, px = col & 15;
    out[idx] = pix[((size_t)b * NTOK + hp * 29 + wp) * DIM + py * 16 + px];
}

// ---------------------------------------------------------------------------
extern "C" void kernel_launch(void* const* d_in, const int* in_sizes, int n_in,
                              void* d_out, int out_size, void* d_ws, size_t ws_size,
                              hipStream_t stream) {
    const float* x     = (const float*)d_in[0];
    const float* pos   = (const float*)d_in[1];
    const float* sptw  = (const float*)d_in[2];
    const float* sptb  = (const float*)d_in[3];
    const float* ln1w  = (const float*)d_in[4];
    const float* ln1b  = (const float*)d_in[5];
    const float* scale = (const float*)d_in[6];
    const float* wqkv  = (const float*)d_in[7];
    const float* wout  = (const float*)d_in[8];
    const float* bout  = (const float*)d_in[9];
    const float* ln2w  = (const float*)d_in[10];
    const float* ln2b  = (const float*)d_in[11];
    const float* ff1w  = (const float*)d_in[12];
    const float* ff1b  = (const float*)d_in[13];
    const float* ff2w  = (const float*)d_in[14];
    const float* ff2b  = (const float*)d_in[15];
    const float* pixw  = (const float*)d_in[16];
    const float* pixb  = (const float*)d_in[17];
    float* out = (float*)d_out;

    const size_t NT = (size_t)ROWS * DIM;   // 1,722,368 elems
    char* ws = (char*)d_ws;
    float* t    = (float*)ws;                         ws += NT * 4;       // fp32 residual
    bf16*  tn_b = (bf16*)ws;                          ws += NT * 2;       // LN out
    bf16*  t_b  = (bf16*)ws;                          ws += NT * 2;       // FF2 bf16 copy
    bf16*  ao_b = (bf16*)ws;                          ws += NT * 2;       // attn out
    bf16*  wbf  = (bf16*)ws;                          ws += (size_t)W_TOTAL * 2;
    char*  big  = ws;                                                      // 20.7MB region
    bf16*  tok  = (bf16*)big;
    float* qkv  = (float*)big;
    bf16*  ffh  = (bf16*)big;
    float* pixo = (float*)big;

    // 0. weight conversion fp32 -> bf16 (packed)
    wconv_kernel<<<W_TOTAL / 4 / 256, 256, 0, stream>>>(sptw, wqkv, wout, ff1w,
                                                        ff2w, pixw, wbf);
    // 1. tokenize gather -> bf16
    tokenize_kernel<<<(ROWS * 320) / 256, 256, 0, stream>>>(x, tok);
    // 2. SPT projection + bias + pos_emb -> t (fp32)
    mfma_gemm_kernel<<<dim3(2, 53), 256, 0, stream>>>(
        tok, wbf + W_SPT, sptb, nullptr, pos, t, nullptr, ROWS, DIM, 1280, 0);

    for (int d = 0; d < 3; d++) {
        ln_kernel<<<ROWS, 256, 0, stream>>>(t, ln1w + d * DIM, ln1b + d * DIM, tn_b);
        // QKV -> fp32
        mfma_gemm_kernel<<<dim3(6, 53), 256, 0, stream>>>(
            tn_b, wbf + W_QKV + (size_t)d * 768 * DIM, nullptr, nullptr, nullptr,
            qkv, nullptr, ROWS, 768, DIM, 0);
        // flash attention -> bf16
        {
            dim3 grid(BATCH * HEADS, (NTOK + 63) / 64);
            attn_flash_kernel<<<grid, 256, 0, stream>>>(qkv, scale + d * HEADS, ao_b);
        }
        // out proj + bias + residual -> t
        mfma_gemm_kernel<<<dim3(2, 53), 256, 0, stream>>>(
            ao_b, wbf + W_OUT + (size_t)d * DIM * DIM, bout + d * DIM, t, nullptr,
            t, nullptr, ROWS, DIM, DIM, 0);
        ln_kernel<<<ROWS, 256, 0, stream>>>(t, ln2w + d * DIM, ln2b + d * DIM, tn_b);
        // FF1 + gelu -> bf16
        mfma_gemm_kernel<<<dim3(8, 53), 256, 0, stream>>>(
            tn_b, wbf + W_FF1 + (size_t)d * 1024 * DIM, ff1b + d * 1024, nullptr,
            nullptr, nullptr, ffh, ROWS, 1024, DIM, 1);
        // FF2 + bias + residual -> t (fp32) and t_b (bf16)
        mfma_gemm_kernel<<<dim3(2, 53), 256, 0, stream>>>(
            ffh, wbf + W_FF2 + (size_t)d * DIM * 1024, ff2b + d * DIM, t, nullptr,
            t, t_b, ROWS, DIM, 1024, 0);
    }

    // pix projection -> fp32 (into big region; ffh/qkv dead)
    mfma_gemm_kernel<<<dim3(2, 53), 256, 0, stream>>>(
        t_b, wbf + W_PIX, pixb, nullptr, nullptr, pixo, nullptr, ROWS, DIM, DIM, 0);
    // scatter to output image
    {
        size_t total = (size_t)BATCH * IMG * IMG;
        scatter_kernel<<<dim3((unsigned)((total + 255) / 256)), 256, 0, stream>>>(pixo, out);
    }
}

// Round 5
// 743.981 us; speedup vs baseline: 3.5110x; 1.2185x over previous
//
#include <hip/hip_runtime.h>
#include <hip/hip_bf16.h>
#include <math.h>

typedef __hip_bfloat16 bf16;
typedef short bf16x8 __attribute__((ext_vector_type(8)));
typedef float floatx4 __attribute__((ext_vector_type(4)));

#define NTOK 841          // 29*29 patches
#define BATCH 8
#define DIM 256
#define HEADS 8
#define DH 32
#define IMG 457
#define HPAD 464
#define ROWS (BATCH * NTOK)   // 6728
#define LDA 40                // padded LDS row stride (bf16 elems) -> 80B

// weight segment offsets (elements) in the packed bf16 weight buffer
#define W_SPT   0
#define W_QKV   327680
#define W_OUT   917504
#define W_FF1   1114112
#define W_FF2   1900544
#define W_PIX   2686976
#define W_TOTAL 2752512

// ---------------------------------------------------------------------------
// Convert all weight tensors fp32 -> bf16 into one packed buffer.
// ---------------------------------------------------------------------------
__global__ __launch_bounds__(256) void wconv_kernel(
    const float* __restrict__ s_spt, const float* __restrict__ s_qkv,
    const float* __restrict__ s_out, const float* __restrict__ s_ff1,
    const float* __restrict__ s_ff2, const float* __restrict__ s_pix,
    bf16* __restrict__ dst) {
    int idx = (blockIdx.x * 256 + threadIdx.x) * 4;
    const float* src; int off;
    if      (idx < W_QKV) { src = s_spt; off = W_SPT; }
    else if (idx < W_OUT) { src = s_qkv; off = W_QKV; }
    else if (idx < W_FF1) { src = s_out; off = W_OUT; }
    else if (idx < W_FF2) { src = s_ff1; off = W_FF1; }
    else if (idx < W_PIX) { src = s_ff2; off = W_FF2; }
    else                  { src = s_pix; off = W_PIX; }
    float4 v = *(const float4*)(src + (idx - off));
    union { ushort4 u; bf16 h[4]; } pk;
    pk.h[0] = __float2bfloat16(v.x);
    pk.h[1] = __float2bfloat16(v.y);
    pk.h[2] = __float2bfloat16(v.z);
    pk.h[3] = __float2bfloat16(v.w);
    *(ushort4*)(dst + idx) = pk.u;
}

// ---------------------------------------------------------------------------
// Tokenize gather -> bf16 tok[ROWS][1280], k=(c,py,px).
// ---------------------------------------------------------------------------
__global__ __launch_bounds__(256) void tokenize_kernel(const float* __restrict__ x,
                                                       bf16* __restrict__ tok) {
    int idx = blockIdx.x * 256 + threadIdx.x;
    int gm = idx / 320;
    int k4 = (idx - gm * 320) * 4;
    int b = gm / NTOK;
    int n = gm - b * NTOK;
    int hp = n / 29, wp = n - (n / 29) * 29;
    int c = k4 >> 8;
    int py = (k4 >> 4) & 15;
    int px0 = k4 & 15;
    const int dxs[5] = {0, -8, 8, -8, 8};
    const int dys[5] = {0, -8, -8, 8, 8};
    int r = hp * 16 + py - dys[c];
    r += (r < 0) ? HPAD : 0; r -= (r >= HPAD) ? HPAD : 0;
    bool rok = (r < IMG);
    union { ushort4 u; bf16 h[4]; } pk;
#pragma unroll
    for (int i = 0; i < 4; i++) {
        int s = wp * 16 + px0 + i - dxs[c];
        s += (s < 0) ? HPAD : 0; s -= (s >= HPAD) ? HPAD : 0;
        float v = 0.0f;
        if (rok && s < IMG) v = x[((size_t)b * IMG + r) * IMG + s];
        pk.h[i] = __float2bfloat16(v);
    }
    *(ushort4*)(tok + (size_t)gm * 1280 + k4) = pk.u;
}

// ---------------------------------------------------------------------------
// MFMA GEMM: C[M,N] = A[M,K]bf16 @ W[N,K]bf16^T, fp32 accum.
// 128x128 block tile, BK=32, 4 waves (2x2 of 64x64), 16x16x32 MFMA.
// ---------------------------------------------------------------------------
__global__ __launch_bounds__(256) void mfma_gemm_kernel(
    const bf16* __restrict__ A, const bf16* __restrict__ W,
    const float* __restrict__ bias, const float* __restrict__ resid,
    const float* __restrict__ posemb, float* __restrict__ Cf,
    bf16* __restrict__ Cb, int M, int N, int K, int act) {
    __shared__ bf16 As[128 * LDA];
    __shared__ bf16 Bs[128 * LDA];
    const int tid = threadIdx.x;
    const int m0 = blockIdx.y * 128, n0 = blockIdx.x * 128;
    const int w = tid >> 6, lane = tid & 63;
    const int wm = (w >> 1) * 64, wn = (w & 1) * 64;
    const int li = lane & 15, quad = lane >> 4;

    floatx4 acc[4][4] = {};

    for (int k0 = 0; k0 < K; k0 += 32) {
#pragma unroll
        for (int i = 0; i < 2; i++) {
            int c = tid + i * 256;
            int row = c >> 2, ko = (c & 3) << 3;
            int gm = m0 + row;
            float4 av = make_float4(0.f, 0.f, 0.f, 0.f);
            if (gm < M) av = *(const float4*)(A + (size_t)gm * K + k0 + ko);
            *(float4*)&As[row * LDA + ko] = av;
            int gn = n0 + row;
            float4 wv = *(const float4*)(W + (size_t)gn * K + k0 + ko);
            *(float4*)&Bs[row * LDA + ko] = wv;
        }
        __syncthreads();
        bf16x8 af[4], bfr[4];
#pragma unroll
        for (int t = 0; t < 4; t++) {
            af[t]  = *(const bf16x8*)&As[(wm + t * 16 + li) * LDA + quad * 8];
            bfr[t] = *(const bf16x8*)&Bs[(wn + t * 16 + li) * LDA + quad * 8];
        }
#pragma unroll
        for (int ti = 0; ti < 4; ti++)
#pragma unroll
            for (int tj = 0; tj < 4; tj++)
                acc[ti][tj] = __builtin_amdgcn_mfma_f32_16x16x32_bf16(
                    af[ti], bfr[tj], acc[ti][tj], 0, 0, 0);
        __syncthreads();
    }

#pragma unroll
    for (int ti = 0; ti < 4; ti++) {
#pragma unroll
        for (int r = 0; r < 4; r++) {
            int gm = m0 + wm + ti * 16 + quad * 4 + r;
            if (gm >= M) continue;
#pragma unroll
            for (int tj = 0; tj < 4; tj++) {
                int gn = n0 + wn + tj * 16 + li;
                float v = acc[ti][tj][r];
                if (bias) v += bias[gn];
                if (act) v = 0.5f * v * (1.0f + erff(v * 0.70710678118654752f));
                if (posemb) v += posemb[(size_t)(gm % NTOK) * N + gn];
                if (resid) v += resid[(size_t)gm * N + gn];
                if (Cf) Cf[(size_t)gm * N + gn] = v;
                if (Cb) Cb[(size_t)gm * N + gn] = __float2bfloat16(v);
            }
        }
    }
}

// ---------------------------------------------------------------------------
// LayerNorm over last dim (256). One wave per row, 4 rows per block.
// fp32 in -> bf16 out. No LDS, shuffle butterfly reduction.
// ---------------------------------------------------------------------------
__global__ __launch_bounds__(256) void ln_kernel(const float* __restrict__ in,
                                                 const float* __restrict__ w,
                                                 const float* __restrict__ b,
                                                 bf16* __restrict__ out) {
    const int lane = threadIdx.x & 63;
    const int wv = threadIdx.x >> 6;
    const size_t row = (size_t)blockIdx.x * 4 + wv;
    const int c = lane * 4;
    float4 x = *(const float4*)&in[row * DIM + c];
    float s = x.x + x.y + x.z + x.w;
    float s2 = x.x * x.x + x.y * x.y + x.z * x.z + x.w * x.w;
#pragma unroll
    for (int off = 1; off < 64; off <<= 1) {
        s += __shfl_xor(s, off);
        s2 += __shfl_xor(s2, off);
    }
    float mean = s * (1.0f / DIM);
    float var = s2 * (1.0f / DIM) - mean * mean;
    float rstd = rsqrtf(var + 1e-5f);
    float4 w4 = *(const float4*)&w[c];
    float4 b4 = *(const float4*)&b[c];
    union { ushort4 u; bf16 h[4]; } pk;
    pk.h[0] = __float2bfloat16((x.x - mean) * rstd * w4.x + b4.x);
    pk.h[1] = __float2bfloat16((x.y - mean) * rstd * w4.y + b4.y);
    pk.h[2] = __float2bfloat16((x.z - mean) * rstd * w4.z + b4.z);
    pk.h[3] = __float2bfloat16((x.w - mean) * rstd * w4.w + b4.w);
    *(ushort4*)&out[row * DIM + c] = pk.u;
}

// ---------------------------------------------------------------------------
// MFMA flash attention. qkv_b bf16 [b, n, 768] (q|k|v). One block per
// (i-tile 64, b*8+h). Strict causal mask j < i; row 0 -> zeros. Output bf16.
// Wave w handles i-rows [w*16, w*16+16). S and PV via 16x16x32 bf16 MFMA.
// ---------------------------------------------------------------------------
#define LQ 40    // Qs/Ks row stride (bf16)
#define LP 72    // Ps/Vt row stride (bf16)
__global__ __launch_bounds__(256) void attn_mfma_kernel(
    const bf16* __restrict__ qkv, const float* __restrict__ scale,
    bf16* __restrict__ out) {
    __shared__ bf16 Qs[64 * LQ];   // [i][d]
    __shared__ bf16 Ks[64 * LQ];   // [j][d]
    __shared__ bf16 Vt[32 * LP];   // [d][j]
    __shared__ bf16 Ps[64 * LP];   // [i][j]

    const int tid = threadIdx.x;
    const int bh = blockIdx.x;
    const int b = bh >> 3, h = bh & 7;
    const int it = (int)gridDim.y - 1 - (int)blockIdx.y;   // longest first
    const int i0 = it * 64;
    const float sc = scale[h];
    const bf16* base = qkv + (size_t)b * NTOK * 768 + h * DH;

    const int w = tid >> 6, lane = tid & 63;
    const int li = lane & 15, quad = lane >> 4;

    // stage Q tile (64 rows x 32 dh)
    {
        int row = tid >> 2, d0 = (tid & 3) * 8;
        int gi = i0 + row;
        bf16x8 v = {};
        if (gi < NTOK) v = *(const bf16x8*)(base + (size_t)gi * 768 + d0);
        *(bf16x8*)&Qs[row * LQ + d0] = v;
    }

    float m[4], l[4];
    floatx4 o[2] = {};
#pragma unroll
    for (int r = 0; r < 4; r++) { m[r] = -1e30f; l[r] = 0.0f; }

    for (int jt = 0; jt <= it; jt++) {
        const int j0 = jt * 64;
        __syncthreads();   // prev PV done reading Ps/Vt; Q staged (first iter)
        // stage K tile and transposed V tile
        {
            int row = tid >> 2, d0 = (tid & 3) * 8;
            int gj = j0 + row;
            bf16x8 kv = {}, vv = {};
            if (gj < NTOK) {
                kv = *(const bf16x8*)(base + (size_t)gj * 768 + 256 + d0);
                vv = *(const bf16x8*)(base + (size_t)gj * 768 + 512 + d0);
            }
            *(bf16x8*)&Ks[row * LQ + d0] = kv;
#pragma unroll
            for (int u = 0; u < 8; u++) Vt[(d0 + u) * LP + row] = ((bf16*)&vv)[u];
        }
        __syncthreads();

        // S = Q K^T : wave w -> 16 i-rows x 64 j-cols, 4 MFMAs
        bf16x8 aq = *(const bf16x8*)&Qs[(w * 16 + li) * LQ + quad * 8];
        floatx4 sacc[4];
#pragma unroll
        for (int tj = 0; tj < 4; tj++) {
            bf16x8 bk = *(const bf16x8*)&Ks[(tj * 16 + li) * LQ + quad * 8];
            floatx4 z = {};
            sacc[tj] = __builtin_amdgcn_mfma_f32_16x16x32_bf16(aq, bk, z, 0, 0, 0);
        }

        // online softmax: lane owns rows (w*16 + quad*4 + r), cols tj*16+li
#pragma unroll
        for (int r = 0; r < 4; r++) {
            const int gi = i0 + w * 16 + quad * 4 + r;
            float sv[4], mloc = -1e30f;
#pragma unroll
            for (int tj = 0; tj < 4; tj++) {
                float v = sacc[tj][r] * sc;
                bool ok = (j0 + tj * 16 + li < gi) && (gi < NTOK);
                sv[tj] = ok ? v : -1e30f;
                mloc = fmaxf(mloc, sv[tj]);
            }
#pragma unroll
            for (int off = 1; off < 16; off <<= 1)
                mloc = fmaxf(mloc, __shfl_xor(mloc, off));
            float mnew = fmaxf(m[r], mloc);
            float alpha = __expf(m[r] - mnew);
            m[r] = mnew;
            float lsum = 0.0f;
#pragma unroll
            for (int tj = 0; tj < 4; tj++) {
                float p = __expf(sv[tj] - mnew);
                sv[tj] = p;
                lsum += p;
            }
#pragma unroll
            for (int off = 1; off < 16; off <<= 1)
                lsum += __shfl_xor(lsum, off);
            l[r] = l[r] * alpha + lsum;
            o[0][r] *= alpha;
            o[1][r] *= alpha;
#pragma unroll
            for (int tj = 0; tj < 4; tj++)
                Ps[(w * 16 + quad * 4 + r) * LP + tj * 16 + li] = __float2bfloat16(sv[tj]);
        }
        __syncthreads();

        // O += P V : wave w's 16 rows x 32 dh; contraction over 64 j (2 k-steps)
#pragma unroll
        for (int kk = 0; kk < 64; kk += 32) {
            bf16x8 ap = *(const bf16x8*)&Ps[(w * 16 + li) * LP + kk + quad * 8];
#pragma unroll
            for (int td = 0; td < 2; td++) {
                bf16x8 bv = *(const bf16x8*)&Vt[(td * 16 + li) * LP + kk + quad * 8];
                o[td] = __builtin_amdgcn_mfma_f32_16x16x32_bf16(ap, bv, o[td], 0, 0, 0);
            }
        }
    }

    // epilogue
#pragma unroll
    for (int r = 0; r < 4; r++) {
        int gi = i0 + w * 16 + quad * 4 + r;
        if (gi >= NTOK) continue;
        float iv = (gi > 0 && l[r] > 0.0f) ? 1.0f / l[r] : 0.0f;
        bf16* op = out + ((size_t)b * NTOK + gi) * DIM + h * DH;
        op[li]      = __float2bfloat16(o[0][r] * iv);
        op[16 + li] = __float2bfloat16(o[1][r] * iv);
    }
}

// ---------------------------------------------------------------------------
// Scatter pix [B, N, 256] fp32 -> out image [B,1,457,457] fp32 (crop)
// ---------------------------------------------------------------------------
__global__ __launch_bounds__(256) void scatter_kernel(const float* __restrict__ pix,
                                                      float* __restrict__ out) {
    const size_t total = (size_t)BATCH * IMG * IMG;
    size_t idx = (size_t)blockIdx.x * 256 + threadIdx.x;
    if (idx >= total) return;
    int b = (int)(idx / ((size_t)IMG * IMG));
    int rem = (int)(idx % ((size_t)IMG * IMG));
    int r = rem / IMG, col = rem % IMG;
    int hp = r >> 4, py = r & 15;
    int wp = col >> 4, px = col & 15;
    out[idx] = pix[((size_t)b * NTOK + hp * 29 + wp) * DIM + py * 16 + px];
}

// ---------------------------------------------------------------------------
extern "C" void kernel_launch(void* const* d_in, const int* in_sizes, int n_in,
                              void* d_out, int out_size, void* d_ws, size_t ws_size,
                              hipStream_t stream) {
    const float* x     = (const float*)d_in[0];
    const float* pos   = (const float*)d_in[1];
    const float* sptw  = (const float*)d_in[2];
    const float* sptb  = (const float*)d_in[3];
    const float* ln1w  = (const float*)d_in[4];
    const float* ln1b  = (const float*)d_in[5];
    const float* scale = (const float*)d_in[6];
    const float* wqkv  = (const float*)d_in[7];
    const float* wout  = (const float*)d_in[8];
    const float* bout  = (const float*)d_in[9];
    const float* ln2w  = (const float*)d_in[10];
    const float* ln2b  = (const float*)d_in[11];
    const float* ff1w  = (const float*)d_in[12];
    const float* ff1b  = (const float*)d_in[13];
    const float* ff2w  = (const float*)d_in[14];
    const float* ff2b  = (const float*)d_in[15];
    const float* pixw  = (const float*)d_in[16];
    const float* pixb  = (const float*)d_in[17];
    float* out = (float*)d_out;

    const size_t NT = (size_t)ROWS * DIM;
    char* ws = (char*)d_ws;
    float* t    = (float*)ws;                         ws += NT * 4;
    bf16*  tn_b = (bf16*)ws;                          ws += NT * 2;
    bf16*  t_b  = (bf16*)ws;                          ws += NT * 2;
    bf16*  ao_b = (bf16*)ws;                          ws += NT * 2;
    bf16*  wbf  = (bf16*)ws;                          ws += (size_t)W_TOTAL * 2;
    char*  big  = ws;                                  // 17.2 MB region, time-shared
    bf16*  tok   = (bf16*)big;
    bf16*  qkv_b = (bf16*)big;
    bf16*  ffh   = (bf16*)big;
    float* pixo  = (float*)big;

    wconv_kernel<<<W_TOTAL / 4 / 256, 256, 0, stream>>>(sptw, wqkv, wout, ff1w,
                                                        ff2w, pixw, wbf);
    tokenize_kernel<<<(ROWS * 320) / 256, 256, 0, stream>>>(x, tok);
    // SPT projection + bias + pos_emb -> t (fp32)
    mfma_gemm_kernel<<<dim3(2, 53), 256, 0, stream>>>(
        tok, wbf + W_SPT, sptb, nullptr, pos, t, nullptr, ROWS, DIM, 1280, 0);

    for (int d = 0; d < 3; d++) {
        ln_kernel<<<ROWS / 4, 256, 0, stream>>>(t, ln1w + d * DIM, ln1b + d * DIM, tn_b);
        // QKV -> bf16
        mfma_gemm_kernel<<<dim3(6, 53), 256, 0, stream>>>(
            tn_b, wbf + W_QKV + (size_t)d * 768 * DIM, nullptr, nullptr, nullptr,
            nullptr, qkv_b, ROWS, 768, DIM, 0);
        // MFMA flash attention -> bf16
        {
            dim3 grid(BATCH * HEADS, (NTOK + 63) / 64);   // (64, 14)
            attn_mfma_kernel<<<grid, 256, 0, stream>>>(qkv_b, scale + d * HEADS, ao_b);
        }
        // out proj + bias + residual -> t
        mfma_gemm_kernel<<<dim3(2, 53), 256, 0, stream>>>(
            ao_b, wbf + W_OUT + (size_t)d * DIM * DIM, bout + d * DIM, t, nullptr,
            t, nullptr, ROWS, DIM, DIM, 0);
        ln_kernel<<<ROWS / 4, 256, 0, stream>>>(t, ln2w + d * DIM, ln2b + d * DIM, tn_b);
        // FF1 + gelu -> bf16
        mfma_gemm_kernel<<<dim3(8, 53), 256, 0, stream>>>(
            tn_b, wbf + W_FF1 + (size_t)d * 1024 * DIM, ff1b + d * 1024, nullptr,
            nullptr, nullptr, ffh, ROWS, 1024, DIM, 1);
        // FF2 + bias + residual -> t (fp32) and t_b (bf16)
        mfma_gemm_kernel<<<dim3(2, 53), 256, 0, stream>>>(
            ffh, wbf + W_FF2 + (size_t)d * DIM * 1024, ff2b + d * DIM, t, nullptr,
            t, t_b, ROWS, DIM, 1024, 0);
    }

    // pix projection -> fp32
    mfma_gemm_kernel<<<dim3(2, 53), 256, 0, stream>>>(
        t_b, wbf + W_PIX, pixb, nullptr, nullptr, pixo, nullptr, ROWS, DIM, DIM, 0);
    {
        size_t total = (size_t)BATCH * IMG * IMG;
        scatter_kernel<<<dim3((unsigned)((total + 255) / 256)), 256, 0, stream>>>(pixo, out);
    }
}

// Round 6
// 546.428 us; speedup vs baseline: 4.7804x; 1.3615x over previous
//
#include <hip/hip_runtime.h>
#include <hip/hip_bf16.h>
#include <math.h>

typedef __hip_bfloat16 bf16;
typedef short bf16x8 __attribute__((ext_vector_type(8)));
typedef float floatx4 __attribute__((ext_vector_type(4)));

#define NTOK 841          // 29*29 patches
#define BATCH 8
#define DIM 256
#define HEADS 8
#define DH 32
#define IMG 457
#define HPAD 464
#define ROWS (BATCH * NTOK)   // 6728
#define LDA 40                // padded LDS row stride (bf16 elems) -> 80B

// weight segment offsets (elements) in the packed bf16 weight buffer
#define W_SPT   0
#define W_QKV   327680
#define W_OUT   917504
#define W_FF1   1114112
#define W_FF2   1900544
#define W_PIX   2686976
#define W_TOTAL 2752512

// ---------------------------------------------------------------------------
// Convert all weight tensors fp32 -> bf16 into one packed buffer.
// ---------------------------------------------------------------------------
__global__ __launch_bounds__(256) void wconv_kernel(
    const float* __restrict__ s_spt, const float* __restrict__ s_qkv,
    const float* __restrict__ s_out, const float* __restrict__ s_ff1,
    const float* __restrict__ s_ff2, const float* __restrict__ s_pix,
    bf16* __restrict__ dst) {
    int idx = (blockIdx.x * 256 + threadIdx.x) * 4;
    const float* src; int off;
    if      (idx < W_QKV) { src = s_spt; off = W_SPT; }
    else if (idx < W_OUT) { src = s_qkv; off = W_QKV; }
    else if (idx < W_FF1) { src = s_out; off = W_OUT; }
    else if (idx < W_FF2) { src = s_ff1; off = W_FF1; }
    else if (idx < W_PIX) { src = s_ff2; off = W_FF2; }
    else                  { src = s_pix; off = W_PIX; }
    float4 v = *(const float4*)(src + (idx - off));
    union { ushort4 u; bf16 h[4]; } pk;
    pk.h[0] = __float2bfloat16(v.x);
    pk.h[1] = __float2bfloat16(v.y);
    pk.h[2] = __float2bfloat16(v.z);
    pk.h[3] = __float2bfloat16(v.w);
    *(ushort4*)(dst + idx) = pk.u;
}

// ---------------------------------------------------------------------------
// Tokenize gather -> bf16 tok[ROWS][1280], k=(c,py,px).
// ---------------------------------------------------------------------------
__global__ __launch_bounds__(256) void tokenize_kernel(const float* __restrict__ x,
                                                       bf16* __restrict__ tok) {
    int idx = blockIdx.x * 256 + threadIdx.x;
    int gm = idx / 320;
    int k4 = (idx - gm * 320) * 4;
    int b = gm / NTOK;
    int n = gm - b * NTOK;
    int hp = n / 29, wp = n - (n / 29) * 29;
    int c = k4 >> 8;
    int py = (k4 >> 4) & 15;
    int px0 = k4 & 15;
    const int dxs[5] = {0, -8, 8, -8, 8};
    const int dys[5] = {0, -8, -8, 8, 8};
    int r = hp * 16 + py - dys[c];
    r += (r < 0) ? HPAD : 0; r -= (r >= HPAD) ? HPAD : 0;
    bool rok = (r < IMG);
    union { ushort4 u; bf16 h[4]; } pk;
#pragma unroll
    for (int i = 0; i < 4; i++) {
        int s = wp * 16 + px0 + i - dxs[c];
        s += (s < 0) ? HPAD : 0; s -= (s >= HPAD) ? HPAD : 0;
        float v = 0.0f;
        if (rok && s < IMG) v = x[((size_t)b * IMG + r) * IMG + s];
        pk.h[i] = __float2bfloat16(v);
    }
    *(ushort4*)(tok + (size_t)gm * 1280 + k4) = pk.u;
}

// ---------------------------------------------------------------------------
// Double-buffered MFMA GEMM: C[M,N] = A[M,K]bf16 @ W[N,K]bf16^T, fp32 accum.
// BMxBN block tile, BK=32, 4 waves (2x2), 16x16x32 MFMA. Register-prefetch
// pipeline: loads for tile kt+1 issued before compute on tile kt.
// N % BN == 0 and K % 32 == 0 required; M bounds-checked.
// ---------------------------------------------------------------------------
template <int BM, int BN>
__global__ __launch_bounds__(256) void gemm_db_kernel(
    const bf16* __restrict__ A, const bf16* __restrict__ W,
    const float* __restrict__ bias, const float* __restrict__ resid,
    const float* __restrict__ posemb, float* __restrict__ Cf,
    bf16* __restrict__ Cb, int M, int N, int K, int act) {
    constexpr int WM = BM / 2, WN = BN / 2;
    constexpr int TI = WM / 16, TJ = WN / 16;
    constexpr int ACH = BM / 64;           // 16B chunks per thread for A tile
    constexpr int BCH = BN / 64;
    __shared__ bf16 As[2][BM * LDA];
    __shared__ bf16 Bs[2][BN * LDA];
    const int tid = threadIdx.x;
    const int m0 = blockIdx.y * BM, n0 = blockIdx.x * BN;
    const int w = tid >> 6, lane = tid & 63;
    const int wm = (w >> 1) * WM, wn = (w & 1) * WN;
    const int li = lane & 15, quad = lane >> 4;

    floatx4 acc[TI][TJ] = {};
    float4 areg[ACH], breg[BCH];

    // prologue: load tile 0
#pragma unroll
    for (int i = 0; i < ACH; i++) {
        int c = tid + i * 256, row = c >> 2, ko = (c & 3) << 3;
        int gm = m0 + row;
        areg[i] = make_float4(0.f, 0.f, 0.f, 0.f);
        if (gm < M) areg[i] = *(const float4*)(A + (size_t)gm * K + ko);
    }
#pragma unroll
    for (int i = 0; i < BCH; i++) {
        int c = tid + i * 256, row = c >> 2, ko = (c & 3) << 3;
        breg[i] = *(const float4*)(W + (size_t)(n0 + row) * K + ko);
    }
#pragma unroll
    for (int i = 0; i < ACH; i++) {
        int c = tid + i * 256;
        *(float4*)&As[0][(c >> 2) * LDA + ((c & 3) << 3)] = areg[i];
    }
#pragma unroll
    for (int i = 0; i < BCH; i++) {
        int c = tid + i * 256;
        *(float4*)&Bs[0][(c >> 2) * LDA + ((c & 3) << 3)] = breg[i];
    }
    __syncthreads();

    const int ktiles = K >> 5;
    for (int kt = 0; kt < ktiles; kt++) {
        const int cur = kt & 1;
        // issue global loads for tile kt+1 (latency covered by compute below)
        if (kt + 1 < ktiles) {
            const int k0 = (kt + 1) << 5;
#pragma unroll
            for (int i = 0; i < ACH; i++) {
                int c = tid + i * 256, row = c >> 2, ko = (c & 3) << 3;
                int gm = m0 + row;
                areg[i] = make_float4(0.f, 0.f, 0.f, 0.f);
                if (gm < M) areg[i] = *(const float4*)(A + (size_t)gm * K + k0 + ko);
            }
#pragma unroll
            for (int i = 0; i < BCH; i++) {
                int c = tid + i * 256, row = c >> 2, ko = (c & 3) << 3;
                breg[i] = *(const float4*)(W + (size_t)(n0 + row) * K + k0 + ko);
            }
        }
        // compute on tile kt
        bf16x8 af[TI], bfr[TJ];
#pragma unroll
        for (int t = 0; t < TI; t++)
            af[t] = *(const bf16x8*)&As[cur][(wm + t * 16 + li) * LDA + quad * 8];
#pragma unroll
        for (int t = 0; t < TJ; t++)
            bfr[t] = *(const bf16x8*)&Bs[cur][(wn + t * 16 + li) * LDA + quad * 8];
#pragma unroll
        for (int ti = 0; ti < TI; ti++)
#pragma unroll
            for (int tj = 0; tj < TJ; tj++)
                acc[ti][tj] = __builtin_amdgcn_mfma_f32_16x16x32_bf16(
                    af[ti], bfr[tj], acc[ti][tj], 0, 0, 0);
        // store tile kt+1 into the other buffer
        if (kt + 1 < ktiles) {
            const int nxt = cur ^ 1;
#pragma unroll
            for (int i = 0; i < ACH; i++) {
                int c = tid + i * 256;
                *(float4*)&As[nxt][(c >> 2) * LDA + ((c & 3) << 3)] = areg[i];
            }
#pragma unroll
            for (int i = 0; i < BCH; i++) {
                int c = tid + i * 256;
                *(float4*)&Bs[nxt][(c >> 2) * LDA + ((c & 3) << 3)] = breg[i];
            }
        }
        __syncthreads();
    }

    // epilogue: C row = quad*4 + reg, col = lane&15
#pragma unroll
    for (int ti = 0; ti < TI; ti++) {
#pragma unroll
        for (int r = 0; r < 4; r++) {
            int gm = m0 + wm + ti * 16 + quad * 4 + r;
            if (gm >= M) continue;
#pragma unroll
            for (int tj = 0; tj < TJ; tj++) {
                int gn = n0 + wn + tj * 16 + li;
                float v = acc[ti][tj][r];
                if (bias) v += bias[gn];
                if (act) v = 0.5f * v * (1.0f + erff(v * 0.70710678118654752f));
                if (posemb) v += posemb[(size_t)(gm % NTOK) * N + gn];
                if (resid) v += resid[(size_t)gm * N + gn];
                if (Cf) Cf[(size_t)gm * N + gn] = v;
                if (Cb) Cb[(size_t)gm * N + gn] = __float2bfloat16(v);
            }
        }
    }
}

// ---------------------------------------------------------------------------
// LayerNorm over last dim (256). One wave per row, 4 rows per block.
// ---------------------------------------------------------------------------
__global__ __launch_bounds__(256) void ln_kernel(const float* __restrict__ in,
                                                 const float* __restrict__ w,
                                                 const float* __restrict__ b,
                                                 bf16* __restrict__ out) {
    const int lane = threadIdx.x & 63;
    const int wv = threadIdx.x >> 6;
    const size_t row = (size_t)blockIdx.x * 4 + wv;
    const int c = lane * 4;
    float4 x = *(const float4*)&in[row * DIM + c];
    float s = x.x + x.y + x.z + x.w;
    float s2 = x.x * x.x + x.y * x.y + x.z * x.z + x.w * x.w;
#pragma unroll
    for (int off = 1; off < 64; off <<= 1) {
        s += __shfl_xor(s, off);
        s2 += __shfl_xor(s2, off);
    }
    float mean = s * (1.0f / DIM);
    float var = s2 * (1.0f / DIM) - mean * mean;
    float rstd = rsqrtf(var + 1e-5f);
    float4 w4 = *(const float4*)&w[c];
    float4 b4 = *(const float4*)&b[c];
    union { ushort4 u; bf16 h[4]; } pk;
    pk.h[0] = __float2bfloat16((x.x - mean) * rstd * w4.x + b4.x);
    pk.h[1] = __float2bfloat16((x.y - mean) * rstd * w4.y + b4.y);
    pk.h[2] = __float2bfloat16((x.z - mean) * rstd * w4.z + b4.z);
    pk.h[3] = __float2bfloat16((x.w - mean) * rstd * w4.w + b4.w);
    *(ushort4*)&out[row * DIM + c] = pk.u;
}

// ---------------------------------------------------------------------------
// MFMA flash attention. qkv_b bf16 [b, n, 768] (q|k|v). One block per
// (i-tile 64, b*8+h). Strict causal mask j < i; row 0 -> zeros. Output bf16.
// ---------------------------------------------------------------------------
#define LQ 40    // Qs/Ks row stride (bf16)
#define LP 72    // Ps/Vt row stride (bf16)
__global__ __launch_bounds__(256) void attn_mfma_kernel(
    const bf16* __restrict__ qkv, const float* __restrict__ scale,
    bf16* __restrict__ out) {
    __shared__ bf16 Qs[64 * LQ];   // [i][d]
    __shared__ bf16 Ks[64 * LQ];   // [j][d]
    __shared__ bf16 Vt[32 * LP];   // [d][j]
    __shared__ bf16 Ps[64 * LP];   // [i][j]

    const int tid = threadIdx.x;
    const int bh = blockIdx.x;
    const int b = bh >> 3, h = bh & 7;
    const int it = (int)gridDim.y - 1 - (int)blockIdx.y;   // longest first
    const int i0 = it * 64;
    const float sc = scale[h];
    const bf16* base = qkv + (size_t)b * NTOK * 768 + h * DH;

    const int w = tid >> 6, lane = tid & 63;
    const int li = lane & 15, quad = lane >> 4;

    // stage Q tile (64 rows x 32 dh)
    {
        int row = tid >> 2, d0 = (tid & 3) * 8;
        int gi = i0 + row;
        bf16x8 v = {};
        if (gi < NTOK) v = *(const bf16x8*)(base + (size_t)gi * 768 + d0);
        *(bf16x8*)&Qs[row * LQ + d0] = v;
    }

    float m[4], l[4];
    floatx4 o[2] = {};
#pragma unroll
    for (int r = 0; r < 4; r++) { m[r] = -1e30f; l[r] = 0.0f; }

    for (int jt = 0; jt <= it; jt++) {
        const int j0 = jt * 64;
        __syncthreads();
        {
            int row = tid >> 2, d0 = (tid & 3) * 8;
            int gj = j0 + row;
            bf16x8 kv = {}, vv = {};
            if (gj < NTOK) {
                kv = *(const bf16x8*)(base + (size_t)gj * 768 + 256 + d0);
                vv = *(const bf16x8*)(base + (size_t)gj * 768 + 512 + d0);
            }
            *(bf16x8*)&Ks[row * LQ + d0] = kv;
#pragma unroll
            for (int u = 0; u < 8; u++) Vt[(d0 + u) * LP + row] = ((bf16*)&vv)[u];
        }
        __syncthreads();

        // S = Q K^T : wave w -> 16 i-rows x 64 j-cols, 4 MFMAs
        bf16x8 aq = *(const bf16x8*)&Qs[(w * 16 + li) * LQ + quad * 8];
        floatx4 sacc[4];
#pragma unroll
        for (int tj = 0; tj < 4; tj++) {
            bf16x8 bk = *(const bf16x8*)&Ks[(tj * 16 + li) * LQ + quad * 8];
            floatx4 z = {};
            sacc[tj] = __builtin_amdgcn_mfma_f32_16x16x32_bf16(aq, bk, z, 0, 0, 0);
        }

        // online softmax
#pragma unroll
        for (int r = 0; r < 4; r++) {
            const int gi = i0 + w * 16 + quad * 4 + r;
            float sv[4], mloc = -1e30f;
#pragma unroll
            for (int tj = 0; tj < 4; tj++) {
                float v = sacc[tj][r] * sc;
                bool ok = (j0 + tj * 16 + li < gi) && (gi < NTOK);
                sv[tj] = ok ? v : -1e30f;
                mloc = fmaxf(mloc, sv[tj]);
            }
#pragma unroll
            for (int off = 1; off < 16; off <<= 1)
                mloc = fmaxf(mloc, __shfl_xor(mloc, off));
            float mnew = fmaxf(m[r], mloc);
            float alpha = __expf(m[r] - mnew);
            m[r] = mnew;
            float lsum = 0.0f;
#pragma unroll
            for (int tj = 0; tj < 4; tj++) {
                float p = __expf(sv[tj] - mnew);
                sv[tj] = p;
                lsum += p;
            }
#pragma unroll
            for (int off = 1; off < 16; off <<= 1)
                lsum += __shfl_xor(lsum, off);
            l[r] = l[r] * alpha + lsum;
            o[0][r] *= alpha;
            o[1][r] *= alpha;
#pragma unroll
            for (int tj = 0; tj < 4; tj++)
                Ps[(w * 16 + quad * 4 + r) * LP + tj * 16 + li] = __float2bfloat16(sv[tj]);
        }
        __syncthreads();

        // O += P V
#pragma unroll
        for (int kk = 0; kk < 64; kk += 32) {
            bf16x8 ap = *(const bf16x8*)&Ps[(w * 16 + li) * LP + kk + quad * 8];
#pragma unroll
            for (int td = 0; td < 2; td++) {
                bf16x8 bv = *(const bf16x8*)&Vt[(td * 16 + li) * LP + kk + quad * 8];
                o[td] = __builtin_amdgcn_mfma_f32_16x16x32_bf16(ap, bv, o[td], 0, 0, 0);
            }
        }
    }

    // epilogue
#pragma unroll
    for (int r = 0; r < 4; r++) {
        int gi = i0 + w * 16 + quad * 4 + r;
        if (gi >= NTOK) continue;
        float iv = (gi > 0 && l[r] > 0.0f) ? 1.0f / l[r] : 0.0f;
        bf16* op = out + ((size_t)b * NTOK + gi) * DIM + h * DH;
        op[li]      = __float2bfloat16(o[0][r] * iv);
        op[16 + li] = __float2bfloat16(o[1][r] * iv);
    }
}

// ---------------------------------------------------------------------------
// Scatter pix [B, N, 256] fp32 -> out image [B,1,457,457] fp32 (crop)
// ---------------------------------------------------------------------------
__global__ __launch_bounds__(256) void scatter_kernel(const float* __restrict__ pix,
                                                      float* __restrict__ out) {
    const size_t total = (size_t)BATCH * IMG * IMG;
    size_t idx = (size_t)blockIdx.x * 256 + threadIdx.x;
    if (idx >= total) return;
    int b = (int)(idx / ((size_t)IMG * IMG));
    int rem = (int)(idx % ((size_t)IMG * IMG));
    int r = rem / IMG, col = rem % IMG;
    int hp = r >> 4, py = r & 15;
    int wp = col >> 4, px = col & 15;
    out[idx] = pix[((size_t)b * NTOK + hp * 29 + wp) * DIM + py * 16 + px];
}

// ---------------------------------------------------------------------------
extern "C" void kernel_launch(void* const* d_in, const int* in_sizes, int n_in,
                              void* d_out, int out_size, void* d_ws, size_t ws_size,
                              hipStream_t stream) {
    const float* x     = (const float*)d_in[0];
    const float* pos   = (const float*)d_in[1];
    const float* sptw  = (const float*)d_in[2];
    const float* sptb  = (const float*)d_in[3];
    const float* ln1w  = (const float*)d_in[4];
    const float* ln1b  = (const float*)d_in[5];
    const float* scale = (const float*)d_in[6];
    const float* wqkv  = (const float*)d_in[7];
    const float* wout  = (const float*)d_in[8];
    const float* bout  = (const float*)d_in[9];
    const float* ln2w  = (const float*)d_in[10];
    const float* ln2b  = (const float*)d_in[11];
    const float* ff1w  = (const float*)d_in[12];
    const float* ff1b  = (const float*)d_in[13];
    const float* ff2w  = (const float*)d_in[14];
    const float* ff2b  = (const float*)d_in[15];
    const float* pixw  = (const float*)d_in[16];
    const float* pixb  = (const float*)d_in[17];
    float* out = (float*)d_out;

    const size_t NT = (size_t)ROWS * DIM;
    char* ws = (char*)d_ws;
    float* t    = (float*)ws;                         ws += NT * 4;
    bf16*  tn_b = (bf16*)ws;                          ws += NT * 2;
    bf16*  t_b  = (bf16*)ws;                          ws += NT * 2;
    bf16*  ao_b = (bf16*)ws;                          ws += NT * 2;
    bf16*  wbf  = (bf16*)ws;                          ws += (size_t)W_TOTAL * 2;
    char*  big  = ws;                                  // 17.2 MB region, time-shared
    bf16*  tok   = (bf16*)big;
    bf16*  qkv_b = (bf16*)big;
    bf16*  ffh   = (bf16*)big;
    float* pixo  = (float*)big;

    wconv_kernel<<<W_TOTAL / 4 / 256, 256, 0, stream>>>(sptw, wqkv, wout, ff1w,
                                                        ff2w, pixw, wbf);
    tokenize_kernel<<<(ROWS * 320) / 256, 256, 0, stream>>>(x, tok);
    // SPT projection + bias + pos_emb -> t (fp32). 64x64 tiles: 424 blocks.
    gemm_db_kernel<64, 64><<<dim3(4, 106), 256, 0, stream>>>(
        tok, wbf + W_SPT, sptb, nullptr, pos, t, nullptr, ROWS, DIM, 1280, 0);

    for (int d = 0; d < 3; d++) {
        ln_kernel<<<ROWS / 4, 256, 0, stream>>>(t, ln1w + d * DIM, ln1b + d * DIM, tn_b);
        // QKV -> bf16 (128x128: 318 blocks)
        gemm_db_kernel<128, 128><<<dim3(6, 53), 256, 0, stream>>>(
            tn_b, wbf + W_QKV + (size_t)d * 768 * DIM, nullptr, nullptr, nullptr,
            nullptr, qkv_b, ROWS, 768, DIM, 0);
        // MFMA flash attention -> bf16
        {
            dim3 grid(BATCH * HEADS, (NTOK + 63) / 64);   // (64, 14)
            attn_mfma_kernel<<<grid, 256, 0, stream>>>(qkv_b, scale + d * HEADS, ao_b);
        }
        // out proj + bias + residual -> t (64x64: 424 blocks)
        gemm_db_kernel<64, 64><<<dim3(4, 106), 256, 0, stream>>>(
            ao_b, wbf + W_OUT + (size_t)d * DIM * DIM, bout + d * DIM, t, nullptr,
            t, nullptr, ROWS, DIM, DIM, 0);
        ln_kernel<<<ROWS / 4, 256, 0, stream>>>(t, ln2w + d * DIM, ln2b + d * DIM, tn_b);
        // FF1 + gelu -> bf16 (128x128: 424 blocks)
        gemm_db_kernel<128, 128><<<dim3(8, 53), 256, 0, stream>>>(
            tn_b, wbf + W_FF1 + (size_t)d * 1024 * DIM, ff1b + d * 1024, nullptr,
            nullptr, nullptr, ffh, ROWS, 1024, DIM, 1);
        // FF2 + bias + residual -> t (fp32) and t_b (bf16) (64x64)
        gemm_db_kernel<64, 64><<<dim3(4, 106), 256, 0, stream>>>(
            ffh, wbf + W_FF2 + (size_t)d * DIM * 1024, ff2b + d * DIM, t, nullptr,
            t, t_b, ROWS, DIM, 1024, 0);
    }

    // pix projection -> fp32 (64x64)
    gemm_db_kernel<64, 64><<<dim3(4, 106), 256, 0, stream>>>(
        t_b, wbf + W_PIX, pixb, nullptr, nullptr, pixo, nullptr, ROWS, DIM, DIM, 0);
    {
        size_t total = (size_t)BATCH * IMG * IMG;
        scatter_kernel<<<dim3((unsigned)((total + 255) / 256)), 256, 0, stream>>>(pixo, out);
    }
}